// Round 1
// baseline (626.260 us; speedup 1.0000x reference)
//
#include <hip/hip_runtime.h>
#include <cmath>

#define E_ 4
#define L_ 10
#define M_ 512
#define F_ 128
#define S_ 1000

typedef unsigned int u32;

__device__ __forceinline__ float fexp2(float a){
#if __has_builtin(__builtin_amdgcn_exp2f)
  return __builtin_amdgcn_exp2f(a);
#else
  return exp2f(a);
#endif
}

// monotone float <-> uint mapping for atomic min/max
__device__ __forceinline__ u32 fenc(float f){
  u32 u = __float_as_uint(f);
  return (u & 0x80000000u) ? ~u : (u | 0x80000000u);
}
__device__ __forceinline__ float fdec(u32 k){
  return __uint_as_float((k & 0x80000000u) ? (k ^ 0x80000000u) : ~k);
}

// ws float layout: [0]=sum of per-(e,l,f) std, [1]=min key(u32), [2]=max key(u32)
// wsf+256   : dpair[6][1280]
// wsf+16384 : proj[E][L][M][F]

__global__ void k_init(float* wsf){
  if (threadIdx.x == 0){
    wsf[0] = 0.0f;
    ((u32*)wsf)[1] = 0xFFFFFFFFu;
    ((u32*)wsf)[2] = 0u;
  }
}

// per-(e,l,f) std over m, summed into wsf[0]
__global__ void k_std(const float* __restrict__ mat, float* __restrict__ wsf){
  __shared__ float S1[512];
  __shared__ float S2[512];
  int b = blockIdx.x;           // (e*L+l) in 0..39
  int tid = threadIdx.x;        // 0..511
  int f = tid & 127, part = tid >> 7;
  const float* base = mat + (size_t)b * M_ * F_;
  float s = 0.f, s2 = 0.f;
  for (int i = 0; i < 128; i++){
    float v = base[(part*128 + i)*F_ + f];
    s += v; s2 += v*v;
  }
  S1[tid] = s; S2[tid] = s2;
  __syncthreads();
  if (part == 0){
    float ts  = S1[f] + S1[f+128] + S1[f+256] + S1[f+384];
    float ts2 = S2[f] + S2[f+128] + S2[f+256] + S2[f+384];
    float mean = ts * (1.0f/512.0f);
    float var  = ts2 * (1.0f/512.0f) - mean*mean;
    var = fmaxf(var, 0.0f);
    S1[f] = sqrtf(var);
  }
  __syncthreads();
  for (int g = 64; g >= 1; g >>= 1){
    if (tid < g) S1[tid] += S1[tid + g];
    __syncthreads();
  }
  if (tid == 0) atomicAdd(&wsf[0], S1[0]);
}

// proj = (matrix/std) @ params, plus global min/max of proj
__global__ void k_gemm(const float* __restrict__ mat, const float* __restrict__ par,
                       float* __restrict__ proj, float* __restrict__ wsf){
  __shared__ float P[F_*F_];                 // 64KB params
  __shared__ __align__(16) float A[16*F_];   // 8KB tile of 16 rows
  __shared__ float R[256];
  int b = blockIdx.x;       // 1280 = 40 * 32
  int el = b >> 5;          // 0..39
  int mt = (b & 31) * 16;   // row tile start
  int tid = threadIdx.x;
  float rstd = 5120.0f / wsf[0];             // 1/std  (std = sum/5120)
  for (int idx = tid; idx < F_*F_; idx += 256) P[idx] = par[idx];
  const float* abase = mat + ((size_t)el * M_ + mt) * F_;
  for (int idx = tid; idx < 16*F_; idx += 256) A[idx] = abase[idx] * rstd;
  __syncthreads();
  int g = tid & 127, half = tid >> 7;
  float o[8];
  #pragma unroll
  for (int r=0;r<8;r++) o[r]=0.f;
  for (int k=0;k<F_;k+=4){
    float pk0 = P[(k+0)*F_+g];
    float pk1 = P[(k+1)*F_+g];
    float pk2 = P[(k+2)*F_+g];
    float pk3 = P[(k+3)*F_+g];
    #pragma unroll
    for (int r=0;r<8;r++){
      const float4 a = *(const float4*)&A[(half*8+r)*F_ + k];
      float t = o[r];
      t = fmaf(a.x, pk0, t);
      t = fmaf(a.y, pk1, t);
      t = fmaf(a.z, pk2, t);
      t = fmaf(a.w, pk3, t);
      o[r] = t;
    }
  }
  float lmin = 3.4e38f, lmax = -3.4e38f;
  #pragma unroll
  for (int r=0;r<8;r++){
    int row = mt + half*8 + r;
    proj[((size_t)el * M_ + row) * F_ + g] = o[r];
    lmin = fminf(lmin, o[r]);
    lmax = fmaxf(lmax, o[r]);
  }
  R[tid] = lmin; __syncthreads();
  for (int s=128; s>=1; s>>=1){ if (tid<s) R[tid]=fminf(R[tid],R[tid+s]); __syncthreads(); }
  if (tid==0) atomicMin(((u32*)wsf)+1, fenc(R[0]));
  __syncthreads();
  R[tid] = lmax; __syncthreads();
  for (int s=128; s>=1; s>>=1){ if (tid<s) R[tid]=fmaxf(R[tid],R[tid+s]); __syncthreads(); }
  if (tid==0) atomicMax(((u32*)wsf)+2, fenc(R[0]));
}

// main KDE: one block per (l,f); computes dpair[6][l*128+f] = sum_t |r_i - r_j|
__global__ void k_kde(const float* __restrict__ proj, const int* __restrict__ dlen,
                      const float* __restrict__ wsf, float* __restrict__ dpair,
                      float k2){
  __shared__ __align__(16) float p[4][M_];   // 8KB: proj columns for 4 envs
  __shared__ float red[256];
  int b = blockIdx.x;          // 0..1279
  int l = b >> 7, f = b & 127;
  int tid = threadIdx.x;
  const u32* wsu = (const u32*)wsf;
  float left  = fdec(wsu[1]);
  float right = fdec(wsu[2]);
  float step = (right - left) / (float)(S_ - 1);   // linspace spacing
  for (int idx = tid; idx < 4*M_; idx += 256){
    int e = idx >> 9, m = idx & (M_-1);
    p[e][m] = proj[(((size_t)e * L_ + l) * M_ + m) * F_ + f];
  }
  float lenf[4];
  #pragma unroll
  for (int e=0;e<4;e++) lenf[e] = (float)dlen[e*L_ + l];
  __syncthreads();

  float x[4];
  float acc[4][4];   // [e][slot]
  #pragma unroll
  for (int r=0;r<4;r++){
    int t = tid + 256*r;
    x[r] = (t < S_) ? (left + (float)t * step) : 1.0e18f;  // inactive -> d2 huge -> exp2 -> 0
    #pragma unroll
    for (int e=0;e<4;e++) acc[e][r] = 0.f;
  }

  for (int m=0;m<M_;m+=4){
    #pragma unroll
    for (int e=0;e<4;e++){
      float4 pq = *(const float4*)&p[e][m];
      float pj4[4] = {pq.x, pq.y, pq.z, pq.w};
      #pragma unroll
      for (int j=0;j<4;j++){
        float pm = pj4[j];
        #pragma unroll
        for (int r=0;r<4;r++){
          float d  = pm - x[r];
          float d2 = d*d;
          // wave-uniform skip: terms with d2>4 are < 2^-31 each (error <<1e-6 on outputs)
          if (__any(d2 < 4.0f))
            acc[e][r] += fexp2(k2 * d2);
        }
      }
    }
  }

  float ps[6] = {0,0,0,0,0,0};
  #pragma unroll
  for (int r=0;r<4;r++){
    int t = tid + 256*r;
    if (t < S_){
      float xv = x[r];
      float cx = fexp2(k2 * xv * xv);       // offset^(x^2)
      float rr[4];
      #pragma unroll
      for (int e=0;e<4;e++)
        rr[e] = (acc[e][r] - (512.0f - lenf[e]) * cx) / lenf[e];
      ps[0] += fabsf(rr[0]-rr[1]);
      ps[1] += fabsf(rr[0]-rr[2]);
      ps[2] += fabsf(rr[0]-rr[3]);
      ps[3] += fabsf(rr[1]-rr[2]);
      ps[4] += fabsf(rr[1]-rr[3]);
      ps[5] += fabsf(rr[2]-rr[3]);
    }
  }
  #pragma unroll
  for (int pr=0; pr<6; pr++){
    red[tid] = ps[pr];
    __syncthreads();
    for (int s=128; s>=1; s>>=1){
      if (tid < s) red[tid] += red[tid+s];
      __syncthreads();
    }
    if (tid == 0) dpair[pr*1280 + b] = red[0];
    __syncthreads();
  }
}

// per-(l,f): scale, masked max over pairs -> train/test results
__global__ void k_final(const float* __restrict__ dpair, const float* __restrict__ wsf,
                        const int* __restrict__ istrain, float* __restrict__ out,
                        float divisor){
  int idx = blockIdx.x * 256 + threadIdx.x;   // 0..1279
  if (idx >= 1280) return;
  const u32* wsu = (const u32*)wsf;
  float left  = fdec(wsu[1]);
  float right = fdec(wsu[2]);
  float delta = (right - left) / (float)S_;
  float hscale = delta * 0.5f;
  bool trn[4];
  #pragma unroll
  for (int e=0;e<4;e++) trn[e] = istrain[e] != 0;
  const int pi[6] = {0,0,0,1,1,2};
  const int pj[6] = {1,2,3,2,3,3};
  float tmax = -INFINITY, trmax = -INFINITY;
  #pragma unroll
  for (int pr=0;pr<6;pr++){
    float h = (dpair[pr*1280 + idx] / divisor) * hscale;
    tmax = fmaxf(tmax, h);
    if (trn[pi[pr]] && trn[pj[pr]]) trmax = fmaxf(trmax, h);
  }
  out[idx]        = trmax;   // train_results
  out[1280 + idx] = tmax;    // test_results
}

// scalars: max over L then mean over F
__global__ void k_scal(float* __restrict__ out){
  __shared__ float s1[128], s2[128];
  int f = threadIdx.x;   // 0..127
  float m1 = -INFINITY, m2 = -INFINITY;
  for (int l=0;l<L_;l++){
    m1 = fmaxf(m1, out[l*F_ + f]);
    m2 = fmaxf(m2, out[1280 + l*F_ + f]);
  }
  s1[f] = m1; s2[f] = m2;
  __syncthreads();
  for (int g=64; g>=1; g>>=1){
    if (f < g){ s1[f] += s1[f+g]; s2[f] += s2[f+g]; }
    __syncthreads();
  }
  if (f == 0){
    out[2560] = s1[0] * (1.0f/128.0f);
    out[2561] = s2[0] * (1.0f/128.0f);
  }
}

extern "C" void kernel_launch(void* const* d_in, const int* in_sizes, int n_in,
                              void* d_out, int out_size, void* d_ws, size_t ws_size,
                              hipStream_t stream){
  const float* mat = (const float*)d_in[0];
  const float* par = (const float*)d_in[1];
  const int*  dlen = (const int*)d_in[2];
  const int*  istr = (const int*)d_in[3];
  float* out   = (float*)d_out;
  float* wsf   = (float*)d_ws;
  float* dpair = wsf + 256;
  float* proj  = wsf + 16384;

  // host-computable constants (bw's data-dependent factor is identically 1)
  double bw_d   = 1.06 * pow(512.0, -0.2);
  float  bw     = (float)bw_d;
  float  offset = expf(-0.5f / (bw*bw));
  float  k2     = (float)(log((double)offset) * 1.4426950408889634);  // log2(offset)
  float  divisor = sqrtf(6.283185307179586f) * bw;

  k_init <<<1,    64,  0, stream>>>(wsf);
  k_std  <<<40,   512, 0, stream>>>(mat, wsf);
  k_gemm <<<1280, 256, 0, stream>>>(mat, par, proj, wsf);
  k_kde  <<<1280, 256, 0, stream>>>(proj, dlen, wsf, dpair, k2);
  k_final<<<5,    256, 0, stream>>>(dpair, wsf, istr, out, divisor);
  k_scal <<<1,    128, 0, stream>>>(out);
}

// Round 2
// 366.279 us; speedup vs baseline: 1.7098x; 1.7098x over previous
//
#include <hip/hip_runtime.h>
#include <cmath>

#define E_ 4
#define L_ 10
#define M_ 512
#define F_ 128
#define S_ 1000

typedef unsigned int u32;

__device__ __forceinline__ float fexp2(float a){
#if __has_builtin(__builtin_amdgcn_exp2f)
  return __builtin_amdgcn_exp2f(a);
#else
  return exp2f(a);
#endif
}

// monotone float <-> uint mapping for atomic min/max
__device__ __forceinline__ u32 fenc(float f){
  u32 u = __float_as_uint(f);
  return (u & 0x80000000u) ? ~u : (u | 0x80000000u);
}
__device__ __forceinline__ float fdec(u32 k){
  return __uint_as_float((k & 0x80000000u) ? (k ^ 0x80000000u) : ~k);
}

// ws float layout: [1]=min key(u32), [2]=max key(u32), [8..48)=std partials
// wsf+256   : dpair[6][1280]
// wsf+16384 : proj[E][L][M][F]

// per-(e,l,f) std over m, partial sums to wsf[8+b]; block 0 inits min/max keys
__global__ void k_std(const float* __restrict__ mat, float* __restrict__ wsf){
  __shared__ float S1[512];
  __shared__ float S2[512];
  int b = blockIdx.x;           // (e*L+l) in 0..39
  int tid = threadIdx.x;        // 0..511
  int f = tid & 127, part = tid >> 7;
  const float* base = mat + (size_t)b * M_ * F_;
  float s = 0.f, s2 = 0.f;
  for (int i = 0; i < 128; i++){
    float v = base[(part*128 + i)*F_ + f];
    s += v; s2 += v*v;
  }
  S1[tid] = s; S2[tid] = s2;
  __syncthreads();
  if (part == 0){
    float ts  = S1[f] + S1[f+128] + S1[f+256] + S1[f+384];
    float ts2 = S2[f] + S2[f+128] + S2[f+256] + S2[f+384];
    float mean = ts * (1.0f/512.0f);
    float var  = ts2 * (1.0f/512.0f) - mean*mean;
    var = fmaxf(var, 0.0f);
    S1[f] = sqrtf(var);
  }
  __syncthreads();
  for (int g = 64; g >= 1; g >>= 1){
    if (tid < g) S1[tid] += S1[tid + g];
    __syncthreads();
  }
  if (tid == 0){
    wsf[8 + b] = S1[0];
    if (b == 0){
      ((u32*)wsf)[1] = 0xFFFFFFFFu;
      ((u32*)wsf)[2] = 0u;
    }
  }
}

// proj = (matrix/std) @ params, plus global min/max of proj
__global__ void k_gemm(const float* __restrict__ mat, const float* __restrict__ par,
                       float* __restrict__ proj, float* __restrict__ wsf){
  __shared__ float P[F_*F_];                 // 64KB params
  __shared__ __align__(16) float A[16*F_];   // 8KB tile of 16 rows
  __shared__ float R[256];
  int b = blockIdx.x;       // 1280 = 40 * 32
  int el = b >> 5;          // 0..39
  int mt = (b & 31) * 16;   // row tile start
  int tid = threadIdx.x;
  float sum = 0.f;
  for (int i = 0; i < 40; i++) sum += wsf[8 + i];
  float rstd = 5120.0f / sum;                // 1/std  (std = sum/5120)
  for (int idx = tid; idx < F_*F_; idx += 256) P[idx] = par[idx];
  const float* abase = mat + ((size_t)el * M_ + mt) * F_;
  for (int idx = tid; idx < 16*F_; idx += 256) A[idx] = abase[idx] * rstd;
  __syncthreads();
  int g = tid & 127, half = tid >> 7;
  float o[8];
  #pragma unroll
  for (int r=0;r<8;r++) o[r]=0.f;
  for (int k=0;k<F_;k+=4){
    float pk0 = P[(k+0)*F_+g];
    float pk1 = P[(k+1)*F_+g];
    float pk2 = P[(k+2)*F_+g];
    float pk3 = P[(k+3)*F_+g];
    #pragma unroll
    for (int r=0;r<8;r++){
      const float4 a = *(const float4*)&A[(half*8+r)*F_ + k];
      float t = o[r];
      t = fmaf(a.x, pk0, t);
      t = fmaf(a.y, pk1, t);
      t = fmaf(a.z, pk2, t);
      t = fmaf(a.w, pk3, t);
      o[r] = t;
    }
  }
  float lmin = 3.4e38f, lmax = -3.4e38f;
  #pragma unroll
  for (int r=0;r<8;r++){
    int row = mt + half*8 + r;
    proj[((size_t)el * M_ + row) * F_ + g] = o[r];
    lmin = fminf(lmin, o[r]);
    lmax = fmaxf(lmax, o[r]);
  }
  R[tid] = lmin; __syncthreads();
  for (int s=128; s>=1; s>>=1){ if (tid<s) R[tid]=fminf(R[tid],R[tid+s]); __syncthreads(); }
  if (tid==0) atomicMin(((u32*)wsf)+1, fenc(R[0]));
  __syncthreads();
  R[tid] = lmax; __syncthreads();
  for (int s=128; s>=1; s>>=1){ if (tid<s) R[tid]=fmaxf(R[tid],R[tid+s]); __syncthreads(); }
  if (tid==0) atomicMax(((u32*)wsf)+2, fenc(R[0]));
}

// main KDE with uniform-grid recurrence:
//   G_t = offset^(d_t^2), d_{t+1} = d_t - step
//   G <- G*R ; R <- R*Q,  R_0 = offset^(step^2 - 2*step*d0), Q = offset^(2*step^2)
// Block = (l,f). 4 waves: wave = {env-pair, m-half}. Lane: env = pair*2 + (lane>>5),
// seg = lane&31 owns t in [seg*32, seg*32+32). 2 exps per m amortized over 32 t.
__global__ __launch_bounds__(256) void k_kde(const float* __restrict__ proj,
                      const int* __restrict__ dlen,
                      const float* __restrict__ wsf, float* __restrict__ dpair,
                      float k2){
  __shared__ __align__(16) float sbuf[8192];  // 32KB: p[4][512] then s[2][4][1024]
  __shared__ float red[32];
  int b = blockIdx.x;          // 0..1279
  int l = b >> 7, f = b & 127;
  int tid = threadIdx.x, wave = tid >> 6, lane = tid & 63;
  // stage p[e][m] at sbuf[e*512+m]
  for (int idx = tid; idx < 2048; idx += 256){
    int e = idx >> 9, m = idx & 511;
    sbuf[idx] = proj[(((size_t)e * L_ + l) * M_ + m) * F_ + f];
  }
  const u32* wsu = (const u32*)wsf;
  float left  = fdec(wsu[1]);
  float right = fdec(wsu[2]);
  float step = (right - left) * (1.0f/999.0f);   // linspace spacing
  float a  = k2 * step * step;
  float bb = -2.0f * k2 * step;
  float Q  = fexp2(2.0f * a);
  int env = ((wave & 1) << 1) | (lane >> 5);
  int mh  = wave >> 1;
  int seg = lane & 31;
  float x0 = left + (float)(seg * 32) * step;
  float lenf4[4];
  #pragma unroll
  for (int e=0;e<4;e++) lenf4[e] = (float)dlen[e*L_ + l];
  float acc[32];
  #pragma unroll
  for (int i=0;i<32;i++) acc[i] = 0.f;
  __syncthreads();
  const float* pp = &sbuf[env*512 + mh*256];
  for (int m = 0; m < 256; m += 2){
    float2 pm = *(const float2*)&pp[m];
    float da = pm.x - x0, db = pm.y - x0;
    float Ga = fexp2(k2*da*da);
    float Ra = fexp2(fmaf(bb, da, a));
    float Gb = fexp2(k2*db*db);
    float Rb = fexp2(fmaf(bb, db, a));
    #pragma unroll
    for (int i=0;i<32;i++){
      acc[i] += Ga + Gb;
      Ga *= Ra; Gb *= Rb;
      Ra *= Q;  Rb *= Q;
    }
  }
  __syncthreads();   // all waves done reading p; reuse sbuf as s[2][4][1024]
  {
    float* dst = &sbuf[mh*4096 + env*1024 + seg*32];
    #pragma unroll
    for (int i=0;i<32;i+=4)
      *(float4*)&dst[i] = make_float4(acc[i], acc[i+1], acc[i+2], acc[i+3]);
  }
  __syncthreads();
  float ps[6] = {0,0,0,0,0,0};
  #pragma unroll
  for (int r=0;r<4;r++){
    int t = tid + 256*r;
    if (t < S_){
      float xv = left + (float)t * step;
      float cx = fexp2(k2 * xv * xv);       // offset^(x^2)
      float rr[4];
      #pragma unroll
      for (int e=0;e<4;e++)
        rr[e] = (sbuf[e*1024 + t] + sbuf[4096 + e*1024 + t]
                 - (512.0f - lenf4[e]) * cx) / lenf4[e];
      ps[0] += fabsf(rr[0]-rr[1]);
      ps[1] += fabsf(rr[0]-rr[2]);
      ps[2] += fabsf(rr[0]-rr[3]);
      ps[3] += fabsf(rr[1]-rr[2]);
      ps[4] += fabsf(rr[1]-rr[3]);
      ps[5] += fabsf(rr[2]-rr[3]);
    }
  }
  #pragma unroll
  for (int pr=0; pr<6; pr++){
    float v = ps[pr];
    #pragma unroll
    for (int d=32; d>=1; d>>=1) v += __shfl_xor(v, d, 64);
    if (lane == 0) red[wave*8 + pr] = v;
  }
  __syncthreads();
  if (tid < 6)
    dpair[tid*1280 + b] = red[tid] + red[8+tid] + red[16+tid] + red[24+tid];
}

// merged finalize: scale, masked max over pairs, then max over L + mean over F
__global__ void k_fin(const float* __restrict__ dpair, const float* __restrict__ wsf,
                      const int* __restrict__ istrain, float* __restrict__ out,
                      float divisor){
  __shared__ float str[1280], ste[1280];
  __shared__ float s1[128], s2[128];
  int tid = threadIdx.x;   // 256 threads, 1 block
  const u32* wsu = (const u32*)wsf;
  float left  = fdec(wsu[1]);
  float right = fdec(wsu[2]);
  float hscale = ((right - left) / (float)S_) * 0.5f / divisor;
  bool t0 = istrain[0]!=0, t1 = istrain[1]!=0, t2 = istrain[2]!=0, t3 = istrain[3]!=0;
  bool trn[6] = { t0&&t1, t0&&t2, t0&&t3, t1&&t2, t1&&t3, t2&&t3 };
  for (int idx = tid; idx < 1280; idx += 256){
    float tmax = -INFINITY, trmax = -INFINITY;
    #pragma unroll
    for (int pr=0;pr<6;pr++){
      float h = dpair[pr*1280 + idx] * hscale;
      tmax = fmaxf(tmax, h);
      if (trn[pr]) trmax = fmaxf(trmax, h);
    }
    out[idx]        = trmax;   // train_results
    out[1280 + idx] = tmax;    // test_results
    str[idx] = trmax; ste[idx] = tmax;
  }
  __syncthreads();
  if (tid < 128){
    float m1 = -INFINITY, m2 = -INFINITY;
    for (int l=0;l<L_;l++){
      m1 = fmaxf(m1, str[l*F_ + tid]);
      m2 = fmaxf(m2, ste[l*F_ + tid]);
    }
    s1[tid] = m1; s2[tid] = m2;
  }
  __syncthreads();
  for (int g=64; g>=1; g>>=1){
    if (tid < g){ s1[tid] += s1[tid+g]; s2[tid] += s2[tid+g]; }
    __syncthreads();
  }
  if (tid == 0){
    out[2560] = s1[0] * (1.0f/128.0f);
    out[2561] = s2[0] * (1.0f/128.0f);
  }
}

extern "C" void kernel_launch(void* const* d_in, const int* in_sizes, int n_in,
                              void* d_out, int out_size, void* d_ws, size_t ws_size,
                              hipStream_t stream){
  const float* mat = (const float*)d_in[0];
  const float* par = (const float*)d_in[1];
  const int*  dlen = (const int*)d_in[2];
  const int*  istr = (const int*)d_in[3];
  float* out   = (float*)d_out;
  float* wsf   = (float*)d_ws;
  float* dpair = wsf + 256;
  float* proj  = wsf + 16384;

  // host-computable constants (bw's data-dependent factor is identically 1)
  double bw_d   = 1.06 * pow(512.0, -0.2);
  float  bw     = (float)bw_d;
  float  offset = expf(-0.5f / (bw*bw));
  float  k2     = (float)(log((double)offset) * 1.4426950408889634);  // log2(offset)
  float  divisor = sqrtf(6.283185307179586f) * bw;

  k_std  <<<40,   512, 0, stream>>>(mat, wsf);
  k_gemm <<<1280, 256, 0, stream>>>(mat, par, proj, wsf);
  k_kde  <<<1280, 256, 0, stream>>>(proj, dlen, wsf, dpair, k2);
  k_fin  <<<1,    256, 0, stream>>>(dpair, wsf, istr, out, divisor);
}

// Round 3
// 195.554 us; speedup vs baseline: 3.2025x; 1.8730x over previous
//
#include <hip/hip_runtime.h>
#include <cmath>

#define E_ 4
#define L_ 10
#define M_ 512
#define F_ 128
#define S_ 1000
#define SC_ 256   // coarse nodes: c=0 at left-stepC, c=1..250 cover grid, +pad

typedef unsigned int u32;

__device__ __forceinline__ float fexp2(float a){
#if __has_builtin(__builtin_amdgcn_exp2f)
  return __builtin_amdgcn_exp2f(a);
#else
  return exp2f(a);
#endif
}

// monotone float <-> uint mapping for atomic min/max
__device__ __forceinline__ u32 fenc(float f){
  u32 u = __float_as_uint(f);
  return (u & 0x80000000u) ? ~u : (u | 0x80000000u);
}
__device__ __forceinline__ float fdec(u32 k){
  return __uint_as_float((k & 0x80000000u) ? (k ^ 0x80000000u) : ~k);
}

// ws float layout: [1]=min key(u32), [2]=max key(u32), [8..48)=std partials
// wsf+256   : dpair[6][1280]
// wsf+16384 : projT[E][L][F][M]   (transposed: m contiguous)

// per-(e,l,f) std over m, partial sums to wsf[8+b]; block 0 inits min/max keys
__global__ void k_std(const float* __restrict__ mat, float* __restrict__ wsf){
  __shared__ float S1[512];
  __shared__ float S2[512];
  int b = blockIdx.x;           // (e*L+l) in 0..39
  int tid = threadIdx.x;        // 0..511
  int f = tid & 127, part = tid >> 7;
  const float* base = mat + (size_t)b * M_ * F_;
  float s = 0.f, s2 = 0.f;
  for (int i = 0; i < 128; i++){
    float v = base[(part*128 + i)*F_ + f];
    s += v; s2 += v*v;
  }
  S1[tid] = s; S2[tid] = s2;
  __syncthreads();
  if (part == 0){
    float ts  = S1[f] + S1[f+128] + S1[f+256] + S1[f+384];
    float ts2 = S2[f] + S2[f+128] + S2[f+256] + S2[f+384];
    float mean = ts * (1.0f/512.0f);
    float var  = ts2 * (1.0f/512.0f) - mean*mean;
    var = fmaxf(var, 0.0f);
    S1[f] = sqrtf(var);
  }
  __syncthreads();
  for (int g = 64; g >= 1; g >>= 1){
    if (tid < g) S1[tid] += S1[tid + g];
    __syncthreads();
  }
  if (tid == 0){
    wsf[8 + b] = S1[0];
    if (b == 0){
      ((u32*)wsf)[1] = 0xFFFFFFFFu;
      ((u32*)wsf)[2] = 0u;
    }
  }
}

// projT[e][l][f][m] = ((matrix/std) @ params) transposed, plus global min/max
__global__ void k_gemm(const float* __restrict__ mat, const float* __restrict__ par,
                       float* __restrict__ projT, float* __restrict__ wsf){
  __shared__ float P[F_*F_];                 // 64KB params
  __shared__ __align__(16) float A[16*F_];   // 8KB tile of 16 rows
  __shared__ float R[256];
  int b = blockIdx.x;       // 1280 = 40 * 32
  int el = b >> 5;          // 0..39
  int mt = (b & 31) * 16;   // row tile start
  int tid = threadIdx.x;
  float sum = 0.f;
  for (int i = 0; i < 40; i++) sum += wsf[8 + i];
  float rstd = 5120.0f / sum;                // 1/std  (std = sum/5120)
  for (int idx = tid; idx < F_*F_; idx += 256) P[idx] = par[idx];
  const float* abase = mat + ((size_t)el * M_ + mt) * F_;
  for (int idx = tid; idx < 16*F_; idx += 256) A[idx] = abase[idx] * rstd;
  __syncthreads();
  int g = tid & 127, half = tid >> 7;
  float o[8];
  #pragma unroll
  for (int r=0;r<8;r++) o[r]=0.f;
  for (int k=0;k<F_;k+=4){
    float pk0 = P[(k+0)*F_+g];
    float pk1 = P[(k+1)*F_+g];
    float pk2 = P[(k+2)*F_+g];
    float pk3 = P[(k+3)*F_+g];
    #pragma unroll
    for (int r=0;r<8;r++){
      const float4 a = *(const float4*)&A[(half*8+r)*F_ + k];
      float t = o[r];
      t = fmaf(a.x, pk0, t);
      t = fmaf(a.y, pk1, t);
      t = fmaf(a.z, pk2, t);
      t = fmaf(a.w, pk3, t);
      o[r] = t;
    }
  }
  // transposed store: rows mt+half*8 .. +8 are contiguous in projT for fixed g
  float* dst = projT + ((size_t)el * F_ + g) * M_ + mt + half*8;
  *(float4*)(dst)     = make_float4(o[0], o[1], o[2], o[3]);
  *(float4*)(dst + 4) = make_float4(o[4], o[5], o[6], o[7]);
  float lmin = 3.4e38f, lmax = -3.4e38f;
  #pragma unroll
  for (int r=0;r<8;r++){
    lmin = fminf(lmin, o[r]);
    lmax = fmaxf(lmax, o[r]);
  }
  R[tid] = lmin; __syncthreads();
  for (int s=128; s>=1; s>>=1){ if (tid<s) R[tid]=fminf(R[tid],R[tid+s]); __syncthreads(); }
  if (tid==0) atomicMin(((u32*)wsf)+1, fenc(R[0]));
  __syncthreads();
  R[tid] = lmax; __syncthreads();
  for (int s=128; s>=1; s>>=1){ if (tid<s) R[tid]=fmaxf(R[tid],R[tid+s]); __syncthreads(); }
  if (tid==0) atomicMax(((u32*)wsf)+2, fenc(R[0]));
}

// KDE on a 4x-coarse grid (geometric recurrence walk), then 4-pt Lagrange cubic
// interpolation to the 1000-pt fine grid. Block = (l,f), 4 waves:
// wave = {pair = w&1, mhalf = w>>1}; half-wave = env = pair*2+(lane>>5);
// lane seg = lane&31 owns coarse nodes [seg*8, seg*8+8).
__global__ __launch_bounds__(256) void k_kde(const float* __restrict__ projT,
                      const int* __restrict__ dlen,
                      const float* __restrict__ wsf, float* __restrict__ dpair,
                      float k2){
  __shared__ __align__(16) float sbuf[2048];  // 8KB: p[4][512], then st[4][256]
  __shared__ float red[32];
  int b = blockIdx.x;          // 0..1279
  int l = b >> 7, f = b & 127;
  int tid = threadIdx.x, wave = tid >> 6, lane = tid & 63;
  // stage p[e][m] (m-contiguous in projT -> coalesced float4)
  for (int idx = tid; idx < 512; idx += 256){
    int e = idx >> 7, mq = idx & 127;
    ((float4*)sbuf)[idx] =
      ((const float4*)(projT + (((size_t)e * L_ + l) * F_ + f) * M_))[mq];
  }
  const u32* wsu = (const u32*)wsf;
  float left  = fdec(wsu[1]);
  float right = fdec(wsu[2]);
  float stepF = (right - left) * (1.0f/999.0f);   // fine linspace spacing
  float stepC = 4.0f * stepF;                     // coarse spacing
  float a  = k2 * stepC * stepC;
  float bb = -2.0f * k2 * stepC;
  float Q  = fexp2(2.0f * a);
  int pair = wave & 1, mh = wave >> 1;
  int env = (pair << 1) | (lane >> 5);
  int seg = lane & 31;
  // coarse node c at x = left + (c-1)*stepC ; this lane starts at c0 = seg*8
  float x0 = left + (float)(seg*8 - 1) * stepC;
  float acc[8];
  #pragma unroll
  for (int i=0;i<8;i++) acc[i] = 0.f;
  __syncthreads();
  const float* pp = &sbuf[env*512 + mh*256];
  for (int m = 0; m < 256; m += 2){
    float2 pm = *(const float2*)&pp[m];
    float da = pm.x - x0, db = pm.y - x0;
    float Ga = fexp2(k2*da*da);
    float Ra = fexp2(fmaf(bb, da, a));
    float Gb = fexp2(k2*db*db);
    float Rb = fexp2(fmaf(bb, db, a));
    #pragma unroll
    for (int i=0;i<8;i++){
      acc[i] += Ga + Gb;
      Ga *= Ra; Gb *= Rb;
      Ra *= Q;  Rb *= Q;
    }
  }
  __syncthreads();   // all waves done reading p; reuse sbuf[0..1023] as st[4][256]
  if (mh == 0){      // waves 0,1 cover all (env,seg) exactly once: store
    #pragma unroll
    for (int i=0;i<8;i++) sbuf[env*256 + seg*8 + i] = acc[i];
  }
  __syncthreads();
  if (mh == 1){      // waves 2,3: accumulate second m-half
    #pragma unroll
    for (int i=0;i<8;i++) sbuf[env*256 + seg*8 + i] += acc[i];
  }
  __syncthreads();
  // fold padding correction + 1/len at coarse nodes: st = (s - (512-len)*offset^(x^2))/len
  for (int idx = tid; idx < 1024; idx += 256){
    int e = idx >> 8, c = idx & 255;
    float lene = (float)dlen[e*L_ + l];
    float xc = left + (float)(c - 1) * stepC;
    float cx = fexp2(k2 * xc * xc);
    sbuf[idx] = (sbuf[idx] - (512.0f - lene) * cx) / lene;
  }
  __syncthreads();
  // fine grid: r_e(t) via 4-pt Lagrange cubic on st, then pairwise L1
  float ps[6] = {0,0,0,0,0,0};
  #pragma unroll
  for (int r=0;r<4;r++){
    int t = tid + 256*r;
    if (t < S_){
      int cc = t >> 2;
      float u = (float)(t & 3) * 0.25f;
      float um1 = u - 1.0f, um2 = u - 2.0f, up1 = u + 1.0f;
      float w0 = -u * um1 * um2 * (1.0f/6.0f);
      float w1 = up1 * um1 * um2 * 0.5f;
      float w2 = -u * up1 * um2 * 0.5f;
      float w3 = u * up1 * um1 * (1.0f/6.0f);
      float rr[4];
      #pragma unroll
      for (int e=0;e<4;e++){
        const float* st = &sbuf[e*256 + cc];
        rr[e] = w0*st[0] + w1*st[1] + w2*st[2] + w3*st[3];
      }
      ps[0] += fabsf(rr[0]-rr[1]);
      ps[1] += fabsf(rr[0]-rr[2]);
      ps[2] += fabsf(rr[0]-rr[3]);
      ps[3] += fabsf(rr[1]-rr[2]);
      ps[4] += fabsf(rr[1]-rr[3]);
      ps[5] += fabsf(rr[2]-rr[3]);
    }
  }
  #pragma unroll
  for (int pr=0; pr<6; pr++){
    float v = ps[pr];
    #pragma unroll
    for (int d=32; d>=1; d>>=1) v += __shfl_xor(v, d, 64);
    if (lane == 0) red[wave*8 + pr] = v;
  }
  __syncthreads();
  if (tid < 6)
    dpair[tid*1280 + b] = red[tid] + red[8+tid] + red[16+tid] + red[24+tid];
}

// merged finalize: scale, masked max over pairs, then max over L + mean over F
__global__ void k_fin(const float* __restrict__ dpair, const float* __restrict__ wsf,
                      const int* __restrict__ istrain, float* __restrict__ out,
                      float divisor){
  __shared__ float str[1280], ste[1280];
  __shared__ float s1[128], s2[128];
  int tid = threadIdx.x;   // 256 threads, 1 block
  const u32* wsu = (const u32*)wsf;
  float left  = fdec(wsu[1]);
  float right = fdec(wsu[2]);
  float hscale = ((right - left) / (float)S_) * 0.5f / divisor;
  bool t0 = istrain[0]!=0, t1 = istrain[1]!=0, t2 = istrain[2]!=0, t3 = istrain[3]!=0;
  bool trn[6] = { t0&&t1, t0&&t2, t0&&t3, t1&&t2, t1&&t3, t2&&t3 };
  for (int idx = tid; idx < 1280; idx += 256){
    float tmax = -INFINITY, trmax = -INFINITY;
    #pragma unroll
    for (int pr=0;pr<6;pr++){
      float h = dpair[pr*1280 + idx] * hscale;
      tmax = fmaxf(tmax, h);
      if (trn[pr]) trmax = fmaxf(trmax, h);
    }
    out[idx]        = trmax;   // train_results
    out[1280 + idx] = tmax;    // test_results
    str[idx] = trmax; ste[idx] = tmax;
  }
  __syncthreads();
  if (tid < 128){
    float m1 = -INFINITY, m2 = -INFINITY;
    for (int l=0;l<L_;l++){
      m1 = fmaxf(m1, str[l*F_ + tid]);
      m2 = fmaxf(m2, ste[l*F_ + tid]);
    }
    s1[tid] = m1; s2[tid] = m2;
  }
  __syncthreads();
  for (int g=64; g>=1; g>>=1){
    if (tid < g){ s1[tid] += s1[tid+g]; s2[tid] += s2[tid+g]; }
    __syncthreads();
  }
  if (tid == 0){
    out[2560] = s1[0] * (1.0f/128.0f);
    out[2561] = s2[0] * (1.0f/128.0f);
  }
}

extern "C" void kernel_launch(void* const* d_in, const int* in_sizes, int n_in,
                              void* d_out, int out_size, void* d_ws, size_t ws_size,
                              hipStream_t stream){
  const float* mat = (const float*)d_in[0];
  const float* par = (const float*)d_in[1];
  const int*  dlen = (const int*)d_in[2];
  const int*  istr = (const int*)d_in[3];
  float* out   = (float*)d_out;
  float* wsf   = (float*)d_ws;
  float* dpair = wsf + 256;
  float* projT = wsf + 16384;

  // host-computable constants (bw's data-dependent factor is identically 1)
  double bw_d   = 1.06 * pow(512.0, -0.2);
  float  bw     = (float)bw_d;
  float  offset = expf(-0.5f / (bw*bw));
  float  k2     = (float)(log((double)offset) * 1.4426950408889634);  // log2(offset)
  float  divisor = sqrtf(6.283185307179586f) * bw;

  k_std  <<<40,   512, 0, stream>>>(mat, wsf);
  k_gemm <<<1280, 256, 0, stream>>>(mat, par, projT, wsf);
  k_kde  <<<1280, 256, 0, stream>>>(projT, dlen, wsf, dpair, k2);
  k_fin  <<<1,    256, 0, stream>>>(dpair, wsf, istr, out, divisor);
}